// Round 1
// 566.894 us; speedup vs baseline: 1.0482x; 1.0482x over previous
//
#include <hip/hip_runtime.h>

// Problem constants (B=2,S=2048,D=1024,E=8,DFF=2048,top_k=2)
#define T_TOK 4096
#define DIM   1024
#define DFF   2048
#define NE    8
#define NR    7    // routed experts (E-1)
#define MAXNB 71   // max routed row-blocks: 8192/128 + 7
#define NY    (32 + MAXNB)   // unified sched entries: 32 e0 + routed

typedef __bf16 bf16x8 __attribute__((ext_vector_type(8)));
typedef float  floatx4 __attribute__((ext_vector_type(4)));

__device__ __forceinline__ unsigned short f32_bf16(float f) {
  union { float f; unsigned int u; } v; v.f = f;
  unsigned int u = v.u;
  unsigned int r = (u + 0x7FFFu + ((u >> 16) & 1u)) >> 16;  // RNE
  return (unsigned short)r;
}

typedef __attribute__((address_space(3))) void lds_void_t;
typedef const __attribute__((address_space(1))) void g_void_t;

__device__ __forceinline__ void gld16(const void* g, void* l) {
  // async global->LDS, 16B/lane; LDS dest = wave-uniform base + lane*16 (m104)
  __builtin_amdgcn_global_load_lds((g_void_t*)g, (lds_void_t*)l, 16, 0, 0);
}

// ---------------- x fp32 -> bf16 ----------------
__global__ __launch_bounds__(256) void cvt_x_kernel(const float4* __restrict__ in,
                                                    ushort4* __restrict__ out) {
  int i = blockIdx.x * 256 + threadIdx.x;
  float4 v = in[i];
  ushort4 o;
  o.x = f32_bf16(v.x); o.y = f32_bf16(v.y);
  o.z = f32_bf16(v.z); o.w = f32_bf16(v.w);
  out[i] = o;
}

// ---------------- router: top-2 -> routed seat lists + per-token records ----------------
__global__ __launch_bounds__(256) void router_kernel(const float* __restrict__ x,
                                                     const float* __restrict__ rw,
                                                     const float* __restrict__ rb,
                                                     int* __restrict__ idxR,
                                                     float* __restrict__ wslR,
                                                     int* __restrict__ cnt,
                                                     int4* __restrict__ tokE,
                                                     float2* __restrict__ tokW) {
  const int lane = threadIdx.x & 63;
  const int t = blockIdx.x * 4 + (threadIdx.x >> 6);  // one wave per token
  const float* xr = x + (size_t)t * DIM;
  float acc[NR];
#pragma unroll
  for (int e = 0; e < NR; e++) acc[e] = 0.f;
  for (int d = lane; d < DIM; d += 64) {
    float xv = xr[d];
#pragma unroll
    for (int e = 0; e < NR; e++) acc[e] += xv * rw[d * NR + e];
  }
#pragma unroll
  for (int off = 32; off > 0; off >>= 1) {
#pragma unroll
    for (int e = 0; e < NR; e++) acc[e] += __shfl_xor(acc[e], off, 64);
  }
  if (lane == 0) {
    float lg[NR];
    float m = -1e30f;
#pragma unroll
    for (int e = 0; e < NR; e++) { lg[e] = acc[e] + rb[e]; m = fmaxf(m, lg[e]); }
    float p[NR], s = 0.f;
#pragma unroll
    for (int e = 0; e < NR; e++) { p[e] = expf(lg[e] - m); s += p[e]; }
#pragma unroll
    for (int e = 0; e < NR; e++) p[e] /= s;
    int i1 = 0;
#pragma unroll
    for (int e = 1; e < NR; e++) if (p[e] > p[i1]) i1 = e;   // ties -> lowest index (jax)
    int i2 = (i1 == 0) ? 1 : 0;
#pragma unroll
    for (int e = 0; e < NR; e++) if (e != i1 && p[e] > p[i2]) i2 = e;
    float w1 = p[i1], w2 = p[i2], sw = w1 + w2;
    float w1n = w1 / sw, w2n = w2 / sw;
    int s1 = atomicAdd(&cnt[i1], 1);
    idxR[i1 * 4096 + s1] = t; wslR[i1 * 4096 + s1] = w1n;
    int s2 = atomicAdd(&cnt[i2], 1);
    idxR[i2 * 4096 + s2] = t; wslR[i2 * 4096 + s2] = w2n;
    int4 te; te.x = i1; te.y = s1; te.z = i2; te.w = s2;
    tokE[t] = te;
    float2 tw; tw.x = w1n; tw.y = w2n;
    tokW[t] = tw;
  }
}

// ---------------- schedule tables ----------------
__global__ __launch_bounds__(256) void sched_kernel(const int* __restrict__ cnt,
                                                    int* __restrict__ idxR,
                                                    float* __restrict__ wslR,
                                                    int4* __restrict__ schedAll,
                                                    int4* __restrict__ schedP,
                                                    int* __restrict__ prefOut,
                                                    int rsb) {
  __shared__ int nb[NR], pref[NR];
  if (threadIdx.x == 0) {
    int p = 0;
    for (int e = 0; e < NR; e++) { int c = cnt[e]; int n = (c + 127) >> 7; nb[e] = n; pref[e] = p; p += n; }
  }
  __syncthreads();
  if (threadIdx.x < NR) prefOut[threadIdx.x] = pref[threadIdx.x];
  for (int e = 0; e < NR; e++) {
    int c = cnt[e], top = nb[e] * 128;
    for (int i = c + (int)threadIdx.x; i < top; i += 256) {
      idxR[e * 4096 + i] = 0; wslR[e * 4096 + i] = 0.f;
    }
  }
  const int NBtot = pref[NR - 1] + nb[NR - 1];
  for (int y = threadIdx.x; y < 32; y += 256) {
    int4 ent; ent.x = 0; ent.y = -1; ent.z = y * 128; ent.w = 0;
    schedAll[y] = ent;
  }
  for (int y = threadIdx.x; y < MAXNB; y += 256) {
    int4 ent; ent.x = -1; ent.y = 0; ent.z = 0; ent.w = 0;
    if (y < NBtot) {
#pragma unroll
      for (int e = 0; e < NR; e++)
        if (y >= pref[e] && y < pref[e] + nb[e]) {
          int rb2 = y - pref[e];
          ent.x = e + 1; ent.y = e * 4096 + rb2 * 128; ent.z = rsb + y * 128;
        }
    }
    schedAll[32 + y] = ent;
  }
  for (int i = threadIdx.x; i < NR * 32; i += 256) {
    int e = i >> 5, rb2 = i & 31;
    int4 ent; ent.w = 0;
    if (rb2 < nb[e]) { ent.x = e + 1; ent.y = e * 4096 + rb2 * 128; ent.z = rb2 * 128; }
    else             { ent.x = -1; ent.y = 0; ent.z = 0; }
    schedP[i] = ent;
  }
}

// ---------------- weight transpose + fp32->bf16 (4B/lane writes) ----------------
__global__ __launch_bounds__(256) void transpose_cvt_kernel(
    const float* __restrict__ wg, const float* __restrict__ wu, const float* __restrict__ wd,
    unsigned short* __restrict__ wgt, unsigned short* __restrict__ wut,
    unsigned short* __restrict__ wdt) {
  __shared__ float tile[64][33];
  const int z = blockIdx.z;
  const float* src; unsigned short* dst; int R, C;
  if (z < 8)       { src = wg + (size_t)z * DIM * DFF;        dst = wgt + (size_t)z * DIM * DFF;        R = DIM; C = DFF; }
  else if (z < 16) { src = wu + (size_t)(z - 8) * DIM * DFF;  dst = wut + (size_t)(z - 8) * DIM * DFF;  R = DIM; C = DFF; }
  else             { src = wd + (size_t)(z - 16) * DFF * DIM; dst = wdt + (size_t)(z - 16) * DFF * DIM; R = DFF; C = DIM; }
  const int c0 = blockIdx.x * 32, r0 = blockIdx.y * 64;
  if (c0 >= C || r0 >= R) return;
  const int tx = threadIdx.x & 31, ty = threadIdx.x >> 5;
#pragma unroll
  for (int j = ty; j < 64; j += 8)
    tile[j][tx] = src[(size_t)(r0 + j) * C + c0 + tx];
  __syncthreads();
#pragma unroll
  for (int j = ty; j < 32; j += 8) {
    unsigned int lo = f32_bf16(tile[2 * tx][j]);
    unsigned int hi = f32_bf16(tile[2 * tx + 1][j]);
    *(unsigned int*)(dst + (size_t)(c0 + j) * R + r0 + 2 * tx) = lo | (hi << 16);
  }
}

// ============ GEMM1 (8-wave, BK=64, 3-buf LDS, phase-interleaved, T2 swizzle) ============
// h[slot] = silu(x[tok]@wg_e)*(x[tok]@wu_e). BM=128 slots, 128 cols of BOTH g and u.
// LDS per buf: A 128x64 | Bg 128x64 | Bu 128x64 (bf16, XOR-swizzled chunks), 3 bufs = 144KB.
// Counted vmcnt(6): 2-tile lookahead, never drained to 0 in the main loop.
__global__ __launch_bounds__(512, 2) void gemm1_kernel(
    const unsigned short* __restrict__ xb, const unsigned short* __restrict__ wgt,
    const unsigned short* __restrict__ wut, const int* __restrict__ idxR,
    const int4* __restrict__ sched, unsigned short* __restrict__ h, int gx) {
  // bijective XCD-aware swizzle (m204)
  const int nblk = gridDim.x;
  int bid = blockIdx.x;
  { int q = nblk >> 3, r = nblk & 7, xc = bid & 7, p = bid >> 3;
    bid = (xc < r ? xc * (q + 1) : r * (q + 1) + (xc - r) * q) + p; }
  const int by = bid / gx, bx = bid - by * gx;
  const int4 ent = sched[by];
  if (ent.x < 0) return;
  __shared__ unsigned short smem[3 * 24576];
  const int tid = threadIdx.x, lane = tid & 63, wid = tid >> 6;
  const int n0 = bx * 128;
  const int wm64 = (wid >> 2) * 64, wn32 = (wid & 3) * 32;
  const int fr = lane & 15, kq8 = lane >> 4, x7 = fr & 7;
  const int r0 = tid >> 3;                      // staged row (and row+64)
  const int c8 = ((tid & 7) ^ (r0 & 7)) * 8;    // inverse-swizzled source column
  int tok0, tok1;
  if (ent.y < 0) { tok0 = ent.z + r0; tok1 = ent.z + r0 + 64; }
  else           { tok0 = idxR[ent.y + r0]; tok1 = idxR[ent.y + r0 + 64]; }
  const unsigned short* wgt_e = wgt + (size_t)ent.x * DIM * DFF;
  const unsigned short* wut_e = wut + (size_t)ent.x * DIM * DFF;
  const unsigned short* gA0 = xb + (size_t)tok0 * DIM + c8;
  const unsigned short* gA1 = xb + (size_t)tok1 * DIM + c8;
  const unsigned short* gG0 = wgt_e + (size_t)(n0 + r0) * DIM + c8;
  const unsigned short* gG1 = gG0 + (size_t)64 * DIM;
  const unsigned short* gU0 = wut_e + (size_t)(n0 + r0) * DIM + c8;
  const unsigned short* gU1 = gU0 + (size_t)64 * DIM;
  // per-lane-constant swizzled fragment offsets (ushort units); row&7 == fr&7
  int offA[2][2], offB[2][2];
#pragma unroll
  for (int mi = 0; mi < 2; mi++)
#pragma unroll
    for (int kk = 0; kk < 2; kk++)
      offA[mi][kk] = (wm64 + mi * 16 + fr) * 64 + (((kk * 4 + kq8) ^ x7) * 8);
#pragma unroll
  for (int ni = 0; ni < 2; ni++)
#pragma unroll
    for (int kk = 0; kk < 2; kk++)
      offB[ni][kk] = (wn32 + ni * 16 + fr) * 64 + (((kk * 4 + kq8) ^ x7) * 8);
  floatx4 accg[4][2], accu[4][2];
  const floatx4 z4 = {0.f, 0.f, 0.f, 0.f};
#pragma unroll
  for (int i = 0; i < 4; i++)
#pragma unroll
    for (int j = 0; j < 2; j++) { accg[i][j] = z4; accu[i][j] = z4; }
  // prologue: stage tiles 0 and 1 (order per tile: A0,A1,G0,G1,U0,U1)
  {
    unsigned short* d = smem + tid * 8;
    gld16(gA0, d);             gld16(gA1, d + 4096);
    gld16(gG0, d + 8192);      gld16(gG1, d + 12288);
    gld16(gU0, d + 16384);     gld16(gU1, d + 20480);
    unsigned short* e = smem + 24576 + tid * 8;
    gld16(gA0 + 64, e);        gld16(gA1 + 64, e + 4096);
    gld16(gG0 + 64, e + 8192); gld16(gG1 + 64, e + 12288);
    gld16(gU0 + 64, e + 16384); gld16(gU1 + 64, e + 20480);
  }
  asm volatile("s_waitcnt vmcnt(6)" ::: "memory");   // tile 0 resident, tile 1 in flight
  __builtin_amdgcn_s_barrier();
  int b = 0;
  for (int k = 0; k < 16; ++k) {
    const unsigned short* Bb = smem + b * 24576;
    int b2 = b + 2; if (b2 >= 3) b2 -= 3;
    unsigned short* db2 = smem + b2 * 24576 + tid * 8;
    const bool pf = (k < 14);
    const int kt = (k + 2) * 64;
    bf16x8 a[2][2], bg[2][2], bu[2][2];
    // ---- phase 0: read A(m0)+Bg | stage A(k+2) | MFMA g(m0)
#pragma unroll
    for (int mi = 0; mi < 2; mi++)
#pragma unroll
      for (int kk = 0; kk < 2; kk++) a[mi][kk] = *(const bf16x8*)(Bb + offA[mi][kk]);
#pragma unroll
    for (int ni = 0; ni < 2; ni++)
#pragma unroll
      for (int kk = 0; kk < 2; kk++) bg[ni][kk] = *(const bf16x8*)(Bb + 8192 + offB[ni][kk]);
    if (pf) { gld16(gA0 + kt, db2); gld16(gA1 + kt, db2 + 4096); }
    __builtin_amdgcn_sched_barrier(0);
    __builtin_amdgcn_s_barrier();
    __builtin_amdgcn_s_setprio(1);
#pragma unroll
    for (int mi = 0; mi < 2; mi++)
#pragma unroll
      for (int ni = 0; ni < 2; ni++)
#pragma unroll
        for (int kk = 0; kk < 2; kk++)
          accg[mi][ni] = __builtin_amdgcn_mfma_f32_16x16x32_bf16(a[mi][kk], bg[ni][kk], accg[mi][ni], 0, 0, 0);
    __builtin_amdgcn_s_setprio(0);
    __builtin_amdgcn_sched_barrier(0);
    __builtin_amdgcn_s_barrier();
    // ---- phase 1: read Bu | stage G(k+2) | MFMA u(m0)
#pragma unroll
    for (int ni = 0; ni < 2; ni++)
#pragma unroll
      for (int kk = 0; kk < 2; kk++) bu[ni][kk] = *(const bf16x8*)(Bb + 16384 + offB[ni][kk]);
    if (pf) { gld16(gG0 + kt, db2 + 8192); gld16(gG1 + kt, db2 + 12288); }
    __builtin_amdgcn_sched_barrier(0);
    __builtin_amdgcn_s_barrier();
    __builtin_amdgcn_s_setprio(1);
#pragma unroll
    for (int mi = 0; mi < 2; mi++)
#pragma unroll
      for (int ni = 0; ni < 2; ni++)
#pragma unroll
        for (int kk = 0; kk < 2; kk++)
          accu[mi][ni] = __builtin_amdgcn_mfma_f32_16x16x32_bf16(a[mi][kk], bu[ni][kk], accu[mi][ni], 0, 0, 0);
    __builtin_amdgcn_s_setprio(0);
    __builtin_amdgcn_sched_barrier(0);
    __builtin_amdgcn_s_barrier();
    // ---- phase 2: read A(m1) | stage U(k+2) | MFMA g(m1)+u(m1) | counted vmcnt
#pragma unroll
    for (int mi = 0; mi < 2; mi++)
#pragma unroll
      for (int kk = 0; kk < 2; kk++) a[mi][kk] = *(const bf16x8*)(Bb + 2048 + offA[mi][kk]);
    if (pf) { gld16(gU0 + kt, db2 + 16384); gld16(gU1 + kt, db2 + 20480); }
    __builtin_amdgcn_sched_barrier(0);
    __builtin_amdgcn_s_barrier();
    __builtin_amdgcn_s_setprio(1);
#pragma unroll
    for (int mi = 0; mi < 2; mi++)
#pragma unroll
      for (int ni = 0; ni < 2; ni++)
#pragma unroll
        for (int kk = 0; kk < 2; kk++) {
          accg[2 + mi][ni] = __builtin_amdgcn_mfma_f32_16x16x32_bf16(a[mi][kk], bg[ni][kk], accg[2 + mi][ni], 0, 0, 0);
          accu[2 + mi][ni] = __builtin_amdgcn_mfma_f32_16x16x32_bf16(a[mi][kk], bu[ni][kk], accu[2 + mi][ni], 0, 0, 0);
        }
    __builtin_amdgcn_s_setprio(0);
    __builtin_amdgcn_sched_barrier(0);
    if (k < 14)       asm volatile("s_waitcnt vmcnt(6)" ::: "memory");
    else if (k == 14) asm volatile("s_waitcnt vmcnt(0)" ::: "memory");
    __builtin_amdgcn_s_barrier();
    b++; if (b == 3) b = 0;
  }
  // epilogue: fused silu(g)*u -> bf16 h
  const int rb = kq8 * 4;
#pragma unroll
  for (int mi = 0; mi < 4; mi++)
#pragma unroll
    for (int ni = 0; ni < 2; ni++)
#pragma unroll
      for (int r = 0; r < 4; r++) {
        int row = ent.z + wm64 + mi * 16 + rb + r;
        int col = n0 + wn32 + ni * 16 + fr;
        float g = accg[mi][ni][r], u = accu[mi][ni][r];
        float hv = (g / (1.f + __expf(-g))) * u;
        h[(size_t)row * DFF + col] = f32_bf16(hv);
      }
}

// ============ GEMM2 (8-wave, BM=128, BN=256, BK=64, same schedule) ============
__global__ __launch_bounds__(512, 2) void gemm2_kernel(
    const unsigned short* __restrict__ hsrc, const unsigned short* __restrict__ wdt,
    const int4* __restrict__ sched, float* __restrict__ y, int gx) {
  const int nblk = gridDim.x;
  int bid = blockIdx.x;
  { int q = nblk >> 3, r = nblk & 7, xc = bid & 7, p = bid >> 3;
    bid = (xc < r ? xc * (q + 1) : r * (q + 1) + (xc - r) * q) + p; }
  const int by = bid / gx, bx = bid - by * gx;
  const int4 ent = sched[by];
  if (ent.x < 0) return;
  __shared__ unsigned short smem[3 * 24576];
  const int tid = threadIdx.x, lane = tid & 63, wid = tid >> 6;
  const int n0 = bx * 256;
  const int wm64 = (wid >> 2) * 64, wn64 = (wid & 3) * 64;
  const int fr = lane & 15, kq8 = lane >> 4, x7 = fr & 7;
  const int r0 = tid >> 3;
  const int c8 = ((tid & 7) ^ (r0 & 7)) * 8;
  const unsigned short* wdt_e = wdt + (size_t)ent.x * DFF * DIM;
  const unsigned short* gA0 = hsrc + (size_t)(ent.z + r0) * DFF + c8;
  const unsigned short* gA1 = gA0 + (size_t)64 * DFF;
  const unsigned short* gB0 = wdt_e + (size_t)(n0 + r0) * DFF + c8;
  const unsigned short* gB1 = gB0 + (size_t)64 * DFF;
  const unsigned short* gB2 = gB0 + (size_t)128 * DFF;
  const unsigned short* gB3 = gB0 + (size_t)192 * DFF;
  int offA[2][2], offB[2][2];
#pragma unroll
  for (int mi = 0; mi < 2; mi++)
#pragma unroll
    for (int kk = 0; kk < 2; kk++)
      offA[mi][kk] = (wm64 + mi * 16 + fr) * 64 + (((kk * 4 + kq8) ^ x7) * 8);
#pragma unroll
  for (int ni = 0; ni < 2; ni++)
#pragma unroll
    for (int kk = 0; kk < 2; kk++)
      offB[ni][kk] = (wn64 + ni * 16 + fr) * 64 + (((kk * 4 + kq8) ^ x7) * 8);
  floatx4 acc[4][4];
  const floatx4 z4 = {0.f, 0.f, 0.f, 0.f};
#pragma unroll
  for (int i = 0; i < 4; i++)
#pragma unroll
    for (int j = 0; j < 4; j++) acc[i][j] = z4;
  // prologue (order per tile: A0,A1,B0,B1,B2,B3)
  {
    unsigned short* d = smem + tid * 8;
    gld16(gA0, d);             gld16(gA1, d + 4096);
    gld16(gB0, d + 8192);      gld16(gB1, d + 12288);
    gld16(gB2, d + 16384);     gld16(gB3, d + 20480);
    unsigned short* e = smem + 24576 + tid * 8;
    gld16(gA0 + 64, e);        gld16(gA1 + 64, e + 4096);
    gld16(gB0 + 64, e + 8192); gld16(gB1 + 64, e + 12288);
    gld16(gB2 + 64, e + 16384); gld16(gB3 + 64, e + 20480);
  }
  asm volatile("s_waitcnt vmcnt(6)" ::: "memory");
  __builtin_amdgcn_s_barrier();
  int b = 0;
  for (int k = 0; k < 32; ++k) {
    const unsigned short* Bb = smem + b * 24576;
    int b2 = b + 2; if (b2 >= 3) b2 -= 3;
    unsigned short* db2 = smem + b2 * 24576 + tid * 8;
    const bool pf = (k < 30);
    const int kt = (k + 2) * 64;
    bf16x8 a[2][2], b0[2][2], b1[2][2];
    // ---- phase 0: read A(m0)+B(n0) | stage A(k+2) | MFMA [m0][n0]
#pragma unroll
    for (int mi = 0; mi < 2; mi++)
#pragma unroll
      for (int kk = 0; kk < 2; kk++) a[mi][kk] = *(const bf16x8*)(Bb + offA[mi][kk]);
#pragma unroll
    for (int ni = 0; ni < 2; ni++)
#pragma unroll
      for (int kk = 0; kk < 2; kk++) b0[ni][kk] = *(const bf16x8*)(Bb + 8192 + offB[ni][kk]);
    if (pf) { gld16(gA0 + kt, db2); gld16(gA1 + kt, db2 + 4096); }
    __builtin_amdgcn_sched_barrier(0);
    __builtin_amdgcn_s_barrier();
    __builtin_amdgcn_s_setprio(1);
#pragma unroll
    for (int mi = 0; mi < 2; mi++)
#pragma unroll
      for (int ni = 0; ni < 2; ni++)
#pragma unroll
        for (int kk = 0; kk < 2; kk++)
          acc[mi][ni] = __builtin_amdgcn_mfma_f32_16x16x32_bf16(a[mi][kk], b0[ni][kk], acc[mi][ni], 0, 0, 0);
    __builtin_amdgcn_s_setprio(0);
    __builtin_amdgcn_sched_barrier(0);
    __builtin_amdgcn_s_barrier();
    // ---- phase 1: read B(n1) | stage B01(k+2) | MFMA [m0][n1]
#pragma unroll
    for (int ni = 0; ni < 2; ni++)
#pragma unroll
      for (int kk = 0; kk < 2; kk++) b1[ni][kk] = *(const bf16x8*)(Bb + 10240 + offB[ni][kk]);
    if (pf) { gld16(gB0 + kt, db2 + 8192); gld16(gB1 + kt, db2 + 12288); }
    __builtin_amdgcn_sched_barrier(0);
    __builtin_amdgcn_s_barrier();
    __builtin_amdgcn_s_setprio(1);
#pragma unroll
    for (int mi = 0; mi < 2; mi++)
#pragma unroll
      for (int ni = 0; ni < 2; ni++)
#pragma unroll
        for (int kk = 0; kk < 2; kk++)
          acc[mi][2 + ni] = __builtin_amdgcn_mfma_f32_16x16x32_bf16(a[mi][kk], b1[ni][kk], acc[mi][2 + ni], 0, 0, 0);
    __builtin_amdgcn_s_setprio(0);
    __builtin_amdgcn_sched_barrier(0);
    __builtin_amdgcn_s_barrier();
    // ---- phase 2: read A(m1) | stage B23(k+2) | MFMA [m1][n0]+[m1][n1] | counted vmcnt
#pragma unroll
    for (int mi = 0; mi < 2; mi++)
#pragma unroll
      for (int kk = 0; kk < 2; kk++) a[mi][kk] = *(const bf16x8*)(Bb + 2048 + offA[mi][kk]);
    if (pf) { gld16(gB2 + kt, db2 + 16384); gld16(gB3 + kt, db2 + 20480); }
    __builtin_amdgcn_sched_barrier(0);
    __builtin_amdgcn_s_barrier();
    __builtin_amdgcn_s_setprio(1);
#pragma unroll
    for (int mi = 0; mi < 2; mi++)
#pragma unroll
      for (int ni = 0; ni < 2; ni++)
#pragma unroll
        for (int kk = 0; kk < 2; kk++) {
          acc[2 + mi][ni]     = __builtin_amdgcn_mfma_f32_16x16x32_bf16(a[mi][kk], b0[ni][kk], acc[2 + mi][ni], 0, 0, 0);
          acc[2 + mi][2 + ni] = __builtin_amdgcn_mfma_f32_16x16x32_bf16(a[mi][kk], b1[ni][kk], acc[2 + mi][2 + ni], 0, 0, 0);
        }
    __builtin_amdgcn_s_setprio(0);
    __builtin_amdgcn_sched_barrier(0);
    if (k < 30)       asm volatile("s_waitcnt vmcnt(6)" ::: "memory");
    else if (k == 30) asm volatile("s_waitcnt vmcnt(0)" ::: "memory");
    __builtin_amdgcn_s_barrier();
    b++; if (b == 3) b = 0;
  }
  const int rb = kq8 * 4;
#pragma unroll
  for (int mi = 0; mi < 4; mi++)
#pragma unroll
    for (int ni = 0; ni < 4; ni++)
#pragma unroll
      for (int r = 0; r < 4; r++)
        y[(size_t)(ent.z + wm64 + mi * 16 + rb + r) * DIM + n0 + wn64 + ni * 16 + fr] = acc[mi][ni][r];
}

// ---------------- GEMM2 atomic variant (fallback modes, unchanged) ----------------
__global__ __launch_bounds__(256) void gemm2_atomic_kernel(
    const unsigned short* __restrict__ h, const unsigned short* __restrict__ wdt,
    const int* __restrict__ idxR, const float* __restrict__ wslR,
    const int4* __restrict__ sched, float* __restrict__ out) {
  const int4 ent = sched[blockIdx.y];
  if (ent.x < 0) return;
  __shared__ unsigned short As[128 * 32];
  __shared__ unsigned short Bs[128 * 32];
  const int tid = threadIdx.x, lane = tid & 63, wid = tid >> 6;
  const int n0 = blockIdx.x * 128;
  const int wm = (wid >> 1) * 64, wn = (wid & 1) * 64;
  floatx4 acc[4][4];
  const floatx4 z4 = {0.f, 0.f, 0.f, 0.f};
#pragma unroll
  for (int i = 0; i < 4; i++)
#pragma unroll
    for (int j = 0; j < 4; j++) acc[i][j] = z4;
  const unsigned short* wdt_e = wdt + (size_t)ent.x * DFF * DIM;
  const int srow = tid >> 2, scol = (tid & 3) * 8;
  const unsigned short* ap0 = h + (size_t)(ent.z + srow) * DFF + scol;
  const unsigned short* ap1 = ap0 + (size_t)64 * DFF;
  const unsigned short* bp0 = wdt_e + (size_t)(n0 + srow) * DFF + scol;
  const unsigned short* bp1 = bp0 + (size_t)64 * DFF;
  unsigned short* as0 = As + tid * 8;
  unsigned short* as1 = As + (256 + tid) * 8;
  unsigned short* bs0 = Bs + tid * 8;
  unsigned short* bs1 = Bs + (256 + tid) * 8;
  const int fr = lane & 15, kq = (lane >> 4) * 8;
  for (int k0 = 0; k0 < DFF; k0 += 32) {
    __syncthreads();
    gld16(ap0 + k0, as0); gld16(ap1 + k0, as1);
    gld16(bp0 + k0, bs0); gld16(bp1 + k0, bs1);
    __syncthreads();
    bf16x8 af[4], bf[4];
#pragma unroll
    for (int mi = 0; mi < 4; mi++) af[mi] = *(const bf16x8*)(As + (wm + mi * 16 + fr) * 32 + kq);
#pragma unroll
    for (int ni = 0; ni < 4; ni++) bf[ni] = *(const bf16x8*)(Bs + (wn + ni * 16 + fr) * 32 + kq);
#pragma unroll
    for (int mi = 0; mi < 4; mi++)
#pragma unroll
      for (int ni = 0; ni < 4; ni++)
        acc[mi][ni] = __builtin_amdgcn_mfma_f32_16x16x32_bf16(af[mi], bf[ni], acc[mi][ni], 0, 0, 0);
  }
  const int rb0 = wm + (lane >> 4) * 4;
  const int cb0 = n0 + wn + fr;
#pragma unroll
  for (int mi = 0; mi < 4; mi++)
#pragma unroll
    for (int r = 0; r < 4; r++) {
      int lrow = rb0 + mi * 16 + r;
      if (ent.y < 0) {
        int tok = ent.z + lrow;
#pragma unroll
        for (int ni = 0; ni < 4; ni++)
          out[(size_t)tok * DIM + cb0 + ni * 16] = acc[mi][ni][r];
      } else {
        int tok = idxR[ent.y + lrow];
        float s = wslR[ent.y + lrow];
        if (s != 0.f) {
#pragma unroll
          for (int ni = 0; ni < 4; ni++)
            atomicAdd(&out[(size_t)tok * DIM + cb0 + ni * 16], s * acc[mi][ni][r]);
        }
      }
    }
}

// ---------------- combine: out[t] = y[t] + w1*y[p1] + w2*y[p2] ----------------
__global__ __launch_bounds__(256) void combine_kernel(const float* __restrict__ y,
                                                      const int4* __restrict__ tokE,
                                                      const float2* __restrict__ tokW,
                                                      const int* __restrict__ pref,
                                                      float* __restrict__ out) {
  const int t = blockIdx.x;
  const int c = threadIdx.x * 4;
  int4 te = tokE[t];
  float2 tw = tokW[t];
  int p1 = 4096 + pref[te.x] * 128 + te.y;
  int p2 = 4096 + pref[te.z] * 128 + te.w;
  float4 a = *(const float4*)(y + (size_t)t * DIM + c);
  float4 b = *(const float4*)(y + (size_t)p1 * DIM + c);
  float4 d = *(const float4*)(y + (size_t)p2 * DIM + c);
  float4 o;
  o.x = a.x + tw.x * b.x + tw.y * d.x;
  o.y = a.y + tw.x * b.y + tw.y * d.y;
  o.z = a.z + tw.x * b.z + tw.y * d.z;
  o.w = a.w + tw.x * b.w + tw.y * d.w;
  *(float4*)(out + (size_t)t * DIM + c) = o;
}

extern "C" void kernel_launch(void* const* d_in, const int* in_sizes, int n_in,
                              void* d_out, int out_size, void* d_ws, size_t ws_size,
                              hipStream_t stream) {
  const float* x  = (const float*)d_in[0];
  const float* rw = (const float*)d_in[1];
  const float* rb = (const float*)d_in[2];
  const float* wg = (const float*)d_in[3];
  const float* wu = (const float*)d_in[4];
  const float* wd = (const float*)d_in[5];
  float* out = (float*)d_out;

  // mode A2: unified, atomic-free (y aliases dead wgt/wut); needs ~163.28 MB (ws known >= 163.32 MB)
  // mode B : sequential e0 + routed, atomic gemm2; needs ~146.7 MB
  // mode C : per-expert loop, atomic gemm2
  const bool modeA = ws_size >= (size_t)163300000;
  const bool modeB = !modeA && ws_size >= (size_t)146700000;
  const size_t H_ROWS = modeA ? 13184 : (modeB ? 9088 : 4096);
  const int rsb = modeA ? 4096 : 0;

  char* p = (char*)d_ws;
  unsigned short* xb  = (unsigned short*)p; p += (size_t)T_TOK * DIM * 2;       // 8,388,608
  unsigned short* h   = (unsigned short*)p; p += H_ROWS * DFF * 2;
  unsigned short* wgt = (unsigned short*)p;                                     // y aliases wgt+wut in mode A
  float*          y   = (float*)p;          p += (size_t)NE * DIM * DFF * 2;
  unsigned short* wut = (unsigned short*)p; p += (size_t)NE * DIM * DFF * 2;
  unsigned short* wdt = (unsigned short*)p; p += (size_t)NE * DIM * DFF * 2;
  int*   idxR = (int*)p;   p += (size_t)NR * 4096 * 4;                          // 114,688
  float* wslR;
  if (modeA) { wslR = (float*)wdt; }                                            // scratch: overwritten by transpose later
  else       { wslR = (float*)p; p += (size_t)NR * 4096 * 4; }
  int*   cnt  = (int*)p;      p += 64;
  int*   pref = (int*)p;      p += 64;
  int4*  schedAll = (int4*)p; p += 2048;
  int4*  schedP   = (int4*)p; p += 4096;
  int4*  tokE = (int4*)p;     p += (size_t)T_TOK * 16;
  float2* tokW = (float2*)p;  p += (size_t)T_TOK * 8;

  cvt_x_kernel<<<dim3(T_TOK * DIM / 4 / 256), 256, 0, stream>>>((const float4*)x, (ushort4*)xb);
  hipMemsetAsync(cnt, 0, 64, stream);
  router_kernel<<<dim3(T_TOK / 4), 256, 0, stream>>>(x, rw, rb, idxR, wslR, cnt, tokE, tokW);
  sched_kernel<<<dim3(1), 256, 0, stream>>>(cnt, idxR, wslR, schedAll, schedP, pref, rsb);
  transpose_cvt_kernel<<<dim3(64, 32, 24), 256, 0, stream>>>(wg, wu, wd, wgt, wut, wdt);

  if (modeA) {
    gemm1_kernel<<<dim3((DFF / 128) * NY), 512, 0, stream>>>(xb, wgt, wut, idxR, schedAll, h, DFF / 128);
    gemm2_kernel<<<dim3((DIM / 256) * NY), 512, 0, stream>>>(h, wdt, schedAll, y, DIM / 256);
    combine_kernel<<<dim3(T_TOK), 256, 0, stream>>>(y, tokE, tokW, pref, out);
  } else if (modeB) {
    gemm1_kernel<<<dim3((DFF / 128) * 32), 512, 0, stream>>>(xb, wgt, wut, idxR, schedAll, h, DFF / 128);
    gemm2_atomic_kernel<<<dim3(DIM / 128, 32), 256, 0, stream>>>(h, wdt, idxR, wslR, schedAll, out);
    gemm1_kernel<<<dim3((DFF / 128) * MAXNB), 512, 0, stream>>>(xb, wgt, wut, idxR, schedAll + 32, h, DFF / 128);
    gemm2_atomic_kernel<<<dim3(DIM / 128, MAXNB), 256, 0, stream>>>(h, wdt, idxR, wslR, schedAll + 32, out);
  } else {
    gemm1_kernel<<<dim3((DFF / 128) * 32), 512, 0, stream>>>(xb, wgt, wut, idxR, schedAll, h, DFF / 128);
    gemm2_atomic_kernel<<<dim3(DIM / 128, 32), 256, 0, stream>>>(h, wdt, idxR, wslR, schedAll, out);
    for (int e = 0; e < NR; e++) {
      gemm1_kernel<<<dim3((DFF / 128) * 32), 512, 0, stream>>>(xb, wgt, wut, idxR, schedP + e * 32, h, DFF / 128);
      gemm2_atomic_kernel<<<dim3(DIM / 128, 32), 256, 0, stream>>>(h, wdt, idxR, wslR, schedP + e * 32, out);
    }
  }
}

// Round 2
// 546.773 us; speedup vs baseline: 1.0868x; 1.0368x over previous
//
#include <hip/hip_runtime.h>

// Problem constants (B=2,S=2048,D=1024,E=8,DFF=2048,top_k=2)
#define T_TOK 4096
#define DIM   1024
#define DFF   2048
#define NE    8
#define NR    7    // routed experts (E-1)
#define MAXNB 71   // max routed row-blocks: 8192/128 + 7
#define NY    (32 + MAXNB)   // unified sched entries: 32 e0 + routed

typedef __bf16 bf16x8 __attribute__((ext_vector_type(8)));
typedef float  floatx4 __attribute__((ext_vector_type(4)));

__device__ __forceinline__ unsigned short f32_bf16(float f) {
  union { float f; unsigned int u; } v; v.f = f;
  unsigned int u = v.u;
  unsigned int r = (u + 0x7FFFu + ((u >> 16) & 1u)) >> 16;  // RNE
  return (unsigned short)r;
}

typedef __attribute__((address_space(3))) void lds_void_t;
typedef const __attribute__((address_space(1))) void g_void_t;

__device__ __forceinline__ void gld16(const void* g, void* l) {
  // async global->LDS, 16B/lane; LDS dest = wave-uniform base + lane*16 (m104)
  __builtin_amdgcn_global_load_lds((g_void_t*)g, (lds_void_t*)l, 16, 0, 0);
}

// ---------------- x fp32 -> bf16 ----------------
__global__ __launch_bounds__(256) void cvt_x_kernel(const float4* __restrict__ in,
                                                    ushort4* __restrict__ out) {
  int i = blockIdx.x * 256 + threadIdx.x;
  float4 v = in[i];
  ushort4 o;
  o.x = f32_bf16(v.x); o.y = f32_bf16(v.y);
  o.z = f32_bf16(v.z); o.w = f32_bf16(v.w);
  out[i] = o;
}

// ---------------- router: top-2 -> routed seat lists + per-token records ----------------
__global__ __launch_bounds__(256) void router_kernel(const float* __restrict__ x,
                                                     const float* __restrict__ rw,
                                                     const float* __restrict__ rb,
                                                     int* __restrict__ idxR,
                                                     float* __restrict__ wslR,
                                                     int* __restrict__ cnt,
                                                     int4* __restrict__ tokE,
                                                     float2* __restrict__ tokW) {
  const int lane = threadIdx.x & 63;
  const int t = blockIdx.x * 4 + (threadIdx.x >> 6);  // one wave per token
  const float* xr = x + (size_t)t * DIM;
  float acc[NR];
#pragma unroll
  for (int e = 0; e < NR; e++) acc[e] = 0.f;
  for (int d = lane; d < DIM; d += 64) {
    float xv = xr[d];
#pragma unroll
    for (int e = 0; e < NR; e++) acc[e] += xv * rw[d * NR + e];
  }
#pragma unroll
  for (int off = 32; off > 0; off >>= 1) {
#pragma unroll
    for (int e = 0; e < NR; e++) acc[e] += __shfl_xor(acc[e], off, 64);
  }
  if (lane == 0) {
    float lg[NR];
    float m = -1e30f;
#pragma unroll
    for (int e = 0; e < NR; e++) { lg[e] = acc[e] + rb[e]; m = fmaxf(m, lg[e]); }
    float p[NR], s = 0.f;
#pragma unroll
    for (int e = 0; e < NR; e++) { p[e] = expf(lg[e] - m); s += p[e]; }
#pragma unroll
    for (int e = 0; e < NR; e++) p[e] /= s;
    int i1 = 0;
#pragma unroll
    for (int e = 1; e < NR; e++) if (p[e] > p[i1]) i1 = e;   // ties -> lowest index (jax)
    int i2 = (i1 == 0) ? 1 : 0;
#pragma unroll
    for (int e = 0; e < NR; e++) if (e != i1 && p[e] > p[i2]) i2 = e;
    float w1 = p[i1], w2 = p[i2], sw = w1 + w2;
    float w1n = w1 / sw, w2n = w2 / sw;
    int s1 = atomicAdd(&cnt[i1], 1);
    idxR[i1 * 4096 + s1] = t; wslR[i1 * 4096 + s1] = w1n;
    int s2 = atomicAdd(&cnt[i2], 1);
    idxR[i2 * 4096 + s2] = t; wslR[i2 * 4096 + s2] = w2n;
    int4 te; te.x = i1; te.y = s1; te.z = i2; te.w = s2;
    tokE[t] = te;
    float2 tw; tw.x = w1n; tw.y = w2n;
    tokW[t] = tw;
  }
}

// ---------------- schedule tables ----------------
__global__ __launch_bounds__(256) void sched_kernel(const int* __restrict__ cnt,
                                                    int* __restrict__ idxR,
                                                    float* __restrict__ wslR,
                                                    int4* __restrict__ schedAll,
                                                    int4* __restrict__ schedP,
                                                    int* __restrict__ prefOut,
                                                    int rsb) {
  __shared__ int nb[NR], pref[NR];
  if (threadIdx.x == 0) {
    int p = 0;
    for (int e = 0; e < NR; e++) { int c = cnt[e]; int n = (c + 127) >> 7; nb[e] = n; pref[e] = p; p += n; }
  }
  __syncthreads();
  if (threadIdx.x < NR) prefOut[threadIdx.x] = pref[threadIdx.x];
  for (int e = 0; e < NR; e++) {
    int c = cnt[e], top = nb[e] * 128;
    for (int i = c + (int)threadIdx.x; i < top; i += 256) {
      idxR[e * 4096 + i] = 0; wslR[e * 4096 + i] = 0.f;
    }
  }
  const int NBtot = pref[NR - 1] + nb[NR - 1];
  for (int y = threadIdx.x; y < 32; y += 256) {
    int4 ent; ent.x = 0; ent.y = -1; ent.z = y * 128; ent.w = 0;
    schedAll[y] = ent;
  }
  for (int y = threadIdx.x; y < MAXNB; y += 256) {
    int4 ent; ent.x = -1; ent.y = 0; ent.z = 0; ent.w = 0;
    if (y < NBtot) {
#pragma unroll
      for (int e = 0; e < NR; e++)
        if (y >= pref[e] && y < pref[e] + nb[e]) {
          int rb2 = y - pref[e];
          ent.x = e + 1; ent.y = e * 4096 + rb2 * 128; ent.z = rsb + y * 128;
        }
    }
    schedAll[32 + y] = ent;
  }
  for (int i = threadIdx.x; i < NR * 32; i += 256) {
    int e = i >> 5, rb2 = i & 31;
    int4 ent; ent.w = 0;
    if (rb2 < nb[e]) { ent.x = e + 1; ent.y = e * 4096 + rb2 * 128; ent.z = rb2 * 128; }
    else             { ent.x = -1; ent.y = 0; ent.z = 0; }
    schedP[i] = ent;
  }
}

// ---------------- weight transpose + fp32->bf16 (4B/lane writes) ----------------
__global__ __launch_bounds__(256) void transpose_cvt_kernel(
    const float* __restrict__ wg, const float* __restrict__ wu, const float* __restrict__ wd,
    unsigned short* __restrict__ wgt, unsigned short* __restrict__ wut,
    unsigned short* __restrict__ wdt) {
  __shared__ float tile[64][33];
  const int z = blockIdx.z;
  const float* src; unsigned short* dst; int R, C;
  if (z < 8)       { src = wg + (size_t)z * DIM * DFF;        dst = wgt + (size_t)z * DIM * DFF;        R = DIM; C = DFF; }
  else if (z < 16) { src = wu + (size_t)(z - 8) * DIM * DFF;  dst = wut + (size_t)(z - 8) * DIM * DFF;  R = DIM; C = DFF; }
  else             { src = wd + (size_t)(z - 16) * DFF * DIM; dst = wdt + (size_t)(z - 16) * DFF * DIM; R = DFF; C = DIM; }
  const int c0 = blockIdx.x * 32, r0 = blockIdx.y * 64;
  if (c0 >= C || r0 >= R) return;
  const int tx = threadIdx.x & 31, ty = threadIdx.x >> 5;
#pragma unroll
  for (int j = ty; j < 64; j += 8)
    tile[j][tx] = src[(size_t)(r0 + j) * C + c0 + tx];
  __syncthreads();
#pragma unroll
  for (int j = ty; j < 32; j += 8) {
    unsigned int lo = f32_bf16(tile[2 * tx][j]);
    unsigned int hi = f32_bf16(tile[2 * tx + 1][j]);
    *(unsigned int*)(dst + (size_t)(c0 + j) * R + r0 + 2 * tx) = lo | (hi << 16);
  }
}

// ============ GEMM1: single-barrier-per-K-tile, BK=64, 3-buf LDS, T2 swizzle ============
// h[slot] = silu(x[tok]@wg_e)*(x[tok]@wu_e). BM=128 slots, 128 cols of BOTH g and u.
// Per K-tile: {issue stage(k+2) | 16x ds_read_b128 | 32-MFMA cluster | vmcnt(6) | s_barrier}.
// The single barrier is both the staging-publication point (after counted vmcnt) and the
// buffer-reuse guard (reads are consumed by MFMA lgkm waits pinned above via sched_barrier).
__global__ __launch_bounds__(512, 2) void gemm1_kernel(
    const unsigned short* __restrict__ xb, const unsigned short* __restrict__ wgt,
    const unsigned short* __restrict__ wut, const int* __restrict__ idxR,
    const int4* __restrict__ sched, unsigned short* __restrict__ h, int gy) {
  // bijective XCD-aware swizzle (m204)
  const int nblk = gridDim.x;
  int bid = blockIdx.x;
  { int q = nblk >> 3, r = nblk & 7, xc = bid & 7, p = bid >> 3;
    bid = (xc < r ? xc * (q + 1) : r * (q + 1) + (xc - r) * q) + p; }
  // by fastest within an XCD chunk: each XCD sweeps all row-blocks for its ~2 weight
  // column-slices (512 KB live weight set, L2-resident) instead of 8 MB/expert per row-block.
  const int bx = bid / gy, by = bid - bx * gy;
  const int4 ent = sched[by];
  if (ent.x < 0) return;
  __shared__ unsigned short smem[3 * 24576];
  const int tid = threadIdx.x, lane = tid & 63, wid = tid >> 6;
  const int n0 = bx * 128;
  const int wm64 = (wid >> 2) * 64, wn32 = (wid & 3) * 32;
  const int fr = lane & 15, kq8 = lane >> 4, x7 = fr & 7;
  const int r0 = tid >> 3;                      // staged row (and row+64)
  const int c8 = ((tid & 7) ^ (r0 & 7)) * 8;    // inverse-swizzled source column
  int tok0, tok1;
  if (ent.y < 0) { tok0 = ent.z + r0; tok1 = ent.z + r0 + 64; }
  else           { tok0 = idxR[ent.y + r0]; tok1 = idxR[ent.y + r0 + 64]; }
  const unsigned short* wgt_e = wgt + (size_t)ent.x * DIM * DFF;
  const unsigned short* wut_e = wut + (size_t)ent.x * DIM * DFF;
  const unsigned short* gA0 = xb + (size_t)tok0 * DIM + c8;
  const unsigned short* gA1 = xb + (size_t)tok1 * DIM + c8;
  const unsigned short* gG0 = wgt_e + (size_t)(n0 + r0) * DIM + c8;
  const unsigned short* gG1 = gG0 + (size_t)64 * DIM;
  const unsigned short* gU0 = wut_e + (size_t)(n0 + r0) * DIM + c8;
  const unsigned short* gU1 = gU0 + (size_t)64 * DIM;
  // per-lane-constant swizzled fragment offsets (ushort units); row&7 == fr&7
  int offA[4][2], offB[2][2];
#pragma unroll
  for (int mi = 0; mi < 4; mi++)
#pragma unroll
    for (int kk = 0; kk < 2; kk++)
      offA[mi][kk] = (wm64 + mi * 16 + fr) * 64 + (((kk * 4 + kq8) ^ x7) * 8);
#pragma unroll
  for (int ni = 0; ni < 2; ni++)
#pragma unroll
    for (int kk = 0; kk < 2; kk++)
      offB[ni][kk] = (wn32 + ni * 16 + fr) * 64 + (((kk * 4 + kq8) ^ x7) * 8);
  floatx4 accg[4][2], accu[4][2];
  const floatx4 z4 = {0.f, 0.f, 0.f, 0.f};
#pragma unroll
  for (int i = 0; i < 4; i++)
#pragma unroll
    for (int j = 0; j < 2; j++) { accg[i][j] = z4; accu[i][j] = z4; }
  // prologue: stage tiles 0 and 1 (order per tile: A0,A1,G0,G1,U0,U1)
  {
    unsigned short* d = smem + tid * 8;
    gld16(gA0, d);             gld16(gA1, d + 4096);
    gld16(gG0, d + 8192);      gld16(gG1, d + 12288);
    gld16(gU0, d + 16384);     gld16(gU1, d + 20480);
    unsigned short* e = smem + 24576 + tid * 8;
    gld16(gA0 + 64, e);        gld16(gA1 + 64, e + 4096);
    gld16(gG0 + 64, e + 8192); gld16(gG1 + 64, e + 12288);
    gld16(gU0 + 64, e + 16384); gld16(gU1 + 64, e + 20480);
  }
  asm volatile("s_waitcnt vmcnt(6)" ::: "memory");   // tile 0 resident, tile 1 in flight
  __builtin_amdgcn_s_barrier();
  int b = 0;
  for (int k = 0; k < 16; ++k) {
    const unsigned short* Bb = smem + b * 24576;
    int b2 = b + 2; if (b2 >= 3) b2 -= 3;
    unsigned short* db2 = smem + b2 * 24576 + tid * 8;
    if (k < 14) {
      const int kt = (k + 2) * 64;
      gld16(gA0 + kt, db2);         gld16(gA1 + kt, db2 + 4096);
      gld16(gG0 + kt, db2 + 8192);  gld16(gG1 + kt, db2 + 12288);
      gld16(gU0 + kt, db2 + 16384); gld16(gU1 + kt, db2 + 20480);
    }
    __builtin_amdgcn_sched_barrier(0);  // pin stage issues before reads
    bf16x8 a[4][2], bg[2][2], bu[2][2];
#pragma unroll
    for (int mi = 0; mi < 4; mi++)
#pragma unroll
      for (int kk = 0; kk < 2; kk++) a[mi][kk] = *(const bf16x8*)(Bb + offA[mi][kk]);
#pragma unroll
    for (int ni = 0; ni < 2; ni++)
#pragma unroll
      for (int kk = 0; kk < 2; kk++) {
        bg[ni][kk] = *(const bf16x8*)(Bb + 8192 + offB[ni][kk]);
        bu[ni][kk] = *(const bf16x8*)(Bb + 16384 + offB[ni][kk]);
      }
    // one big MFMA cluster; compiler interleaves fine-grained lgkmcnt waits
    __builtin_amdgcn_s_setprio(1);
#pragma unroll
    for (int mi = 0; mi < 4; mi++)
#pragma unroll
      for (int ni = 0; ni < 2; ni++)
#pragma unroll
        for (int kk = 0; kk < 2; kk++)
          accg[mi][ni] = __builtin_amdgcn_mfma_f32_16x16x32_bf16(a[mi][kk], bg[ni][kk], accg[mi][ni], 0, 0, 0);
#pragma unroll
    for (int mi = 0; mi < 4; mi++)
#pragma unroll
      for (int ni = 0; ni < 2; ni++)
#pragma unroll
        for (int kk = 0; kk < 2; kk++)
          accu[mi][ni] = __builtin_amdgcn_mfma_f32_16x16x32_bf16(a[mi][kk], bu[ni][kk], accu[mi][ni], 0, 0, 0);
    __builtin_amdgcn_s_setprio(0);
    __builtin_amdgcn_sched_barrier(0);  // rule #18: nothing sinks past the barrier
    if (k < 14)       asm volatile("s_waitcnt vmcnt(6)" ::: "memory");
    else if (k == 14) asm volatile("s_waitcnt vmcnt(0)" ::: "memory");
    __builtin_amdgcn_s_barrier();
    b++; if (b == 3) b = 0;
  }
  // epilogue: fused silu(g)*u -> bf16 h
  const int rb = kq8 * 4;
#pragma unroll
  for (int mi = 0; mi < 4; mi++)
#pragma unroll
    for (int ni = 0; ni < 2; ni++)
#pragma unroll
      for (int r = 0; r < 4; r++) {
        int row = ent.z + wm64 + mi * 16 + rb + r;
        int col = n0 + wn32 + ni * 16 + fr;
        float g = accg[mi][ni][r], u = accu[mi][ni][r];
        float hv = (g / (1.f + __expf(-g))) * u;
        h[(size_t)row * DFF + col] = f32_bf16(hv);
      }
}

// ============ GEMM2: single-barrier-per-K-tile, BM=128, BN=256, BK=64 ============
__global__ __launch_bounds__(512, 2) void gemm2_kernel(
    const unsigned short* __restrict__ hsrc, const unsigned short* __restrict__ wdt,
    const int4* __restrict__ sched, float* __restrict__ y, int gx) {
  const int nblk = gridDim.x;
  int bid = blockIdx.x;
  { int q = nblk >> 3, r = nblk & 7, xc = bid & 7, p = bid >> 3;
    bid = (xc < r ? xc * (q + 1) : r * (q + 1) + (xc - r) * q) + p; }
  const int by = bid / gx, bx = bid - by * gx;   // bx inner: h-tile reused across bx in L2
  const int4 ent = sched[by];
  if (ent.x < 0) return;
  __shared__ unsigned short smem[3 * 24576];
  const int tid = threadIdx.x, lane = tid & 63, wid = tid >> 6;
  const int n0 = bx * 256;
  const int wm64 = (wid >> 2) * 64, wn64 = (wid & 3) * 64;
  const int fr = lane & 15, kq8 = lane >> 4, x7 = fr & 7;
  const int r0 = tid >> 3;
  const int c8 = ((tid & 7) ^ (r0 & 7)) * 8;
  const unsigned short* wdt_e = wdt + (size_t)ent.x * DFF * DIM;
  const unsigned short* gA0 = hsrc + (size_t)(ent.z + r0) * DFF + c8;
  const unsigned short* gA1 = gA0 + (size_t)64 * DFF;
  const unsigned short* gB0 = wdt_e + (size_t)(n0 + r0) * DFF + c8;
  const unsigned short* gB1 = gB0 + (size_t)64 * DFF;
  const unsigned short* gB2 = gB0 + (size_t)128 * DFF;
  const unsigned short* gB3 = gB0 + (size_t)192 * DFF;
  int offA[4][2], offB[2][2];
#pragma unroll
  for (int mi = 0; mi < 4; mi++)
#pragma unroll
    for (int kk = 0; kk < 2; kk++)
      offA[mi][kk] = (wm64 + mi * 16 + fr) * 64 + (((kk * 4 + kq8) ^ x7) * 8);
#pragma unroll
  for (int ni = 0; ni < 2; ni++)
#pragma unroll
    for (int kk = 0; kk < 2; kk++)
      offB[ni][kk] = (wn64 + ni * 16 + fr) * 64 + (((kk * 4 + kq8) ^ x7) * 8);
  floatx4 acc[4][4];
  const floatx4 z4 = {0.f, 0.f, 0.f, 0.f};
#pragma unroll
  for (int i = 0; i < 4; i++)
#pragma unroll
    for (int j = 0; j < 4; j++) acc[i][j] = z4;
  // prologue (order per tile: A0,A1,B0,B1,B2,B3)
  {
    unsigned short* d = smem + tid * 8;
    gld16(gA0, d);             gld16(gA1, d + 4096);
    gld16(gB0, d + 8192);      gld16(gB1, d + 12288);
    gld16(gB2, d + 16384);     gld16(gB3, d + 20480);
    unsigned short* e = smem + 24576 + tid * 8;
    gld16(gA0 + 64, e);        gld16(gA1 + 64, e + 4096);
    gld16(gB0 + 64, e + 8192); gld16(gB1 + 64, e + 12288);
    gld16(gB2 + 64, e + 16384); gld16(gB3 + 64, e + 20480);
  }
  asm volatile("s_waitcnt vmcnt(6)" ::: "memory");
  __builtin_amdgcn_s_barrier();
  int b = 0;
  for (int k = 0; k < 32; ++k) {
    const unsigned short* Bb = smem + b * 24576;
    int b2 = b + 2; if (b2 >= 3) b2 -= 3;
    unsigned short* db2 = smem + b2 * 24576 + tid * 8;
    if (k < 30) {
      const int kt = (k + 2) * 64;
      gld16(gA0 + kt, db2);         gld16(gA1 + kt, db2 + 4096);
      gld16(gB0 + kt, db2 + 8192);  gld16(gB1 + kt, db2 + 12288);
      gld16(gB2 + kt, db2 + 16384); gld16(gB3 + kt, db2 + 20480);
    }
    __builtin_amdgcn_sched_barrier(0);
    bf16x8 a[4][2], b0[2][2], b1[2][2];
#pragma unroll
    for (int mi = 0; mi < 4; mi++)
#pragma unroll
      for (int kk = 0; kk < 2; kk++) a[mi][kk] = *(const bf16x8*)(Bb + offA[mi][kk]);
#pragma unroll
    for (int ni = 0; ni < 2; ni++)
#pragma unroll
      for (int kk = 0; kk < 2; kk++) {
        b0[ni][kk] = *(const bf16x8*)(Bb + 8192 + offB[ni][kk]);
        b1[ni][kk] = *(const bf16x8*)(Bb + 10240 + offB[ni][kk]);
      }
    __builtin_amdgcn_s_setprio(1);
#pragma unroll
    for (int mi = 0; mi < 4; mi++)
#pragma unroll
      for (int ni = 0; ni < 2; ni++)
#pragma unroll
        for (int kk = 0; kk < 2; kk++) {
          acc[mi][ni]     = __builtin_amdgcn_mfma_f32_16x16x32_bf16(a[mi][kk], b0[ni][kk], acc[mi][ni], 0, 0, 0);
          acc[mi][2 + ni] = __builtin_amdgcn_mfma_f32_16x16x32_bf16(a[mi][kk], b1[ni][kk], acc[mi][2 + ni], 0, 0, 0);
        }
    __builtin_amdgcn_s_setprio(0);
    __builtin_amdgcn_sched_barrier(0);
    if (k < 30)       asm volatile("s_waitcnt vmcnt(6)" ::: "memory");
    else if (k == 30) asm volatile("s_waitcnt vmcnt(0)" ::: "memory");
    __builtin_amdgcn_s_barrier();
    b++; if (b == 3) b = 0;
  }
  const int rb = kq8 * 4;
#pragma unroll
  for (int mi = 0; mi < 4; mi++)
#pragma unroll
    for (int ni = 0; ni < 4; ni++)
#pragma unroll
      for (int r = 0; r < 4; r++)
        y[(size_t)(ent.z + wm64 + mi * 16 + rb + r) * DIM + n0 + wn64 + ni * 16 + fr] = acc[mi][ni][r];
}

// ---------------- GEMM2 atomic variant (fallback modes, unchanged) ----------------
__global__ __launch_bounds__(256) void gemm2_atomic_kernel(
    const unsigned short* __restrict__ h, const unsigned short* __restrict__ wdt,
    const int* __restrict__ idxR, const float* __restrict__ wslR,
    const int4* __restrict__ sched, float* __restrict__ out) {
  const int4 ent = sched[blockIdx.y];
  if (ent.x < 0) return;
  __shared__ unsigned short As[128 * 32];
  __shared__ unsigned short Bs[128 * 32];
  const int tid = threadIdx.x, lane = tid & 63, wid = tid >> 6;
  const int n0 = blockIdx.x * 128;
  const int wm = (wid >> 1) * 64, wn = (wid & 1) * 64;
  floatx4 acc[4][4];
  const floatx4 z4 = {0.f, 0.f, 0.f, 0.f};
#pragma unroll
  for (int i = 0; i < 4; i++)
#pragma unroll
    for (int j = 0; j < 4; j++) acc[i][j] = z4;
  const unsigned short* wdt_e = wdt + (size_t)ent.x * DFF * DIM;
  const int srow = tid >> 2, scol = (tid & 3) * 8;
  const unsigned short* ap0 = h + (size_t)(ent.z + srow) * DFF + scol;
  const unsigned short* ap1 = ap0 + (size_t)64 * DFF;
  const unsigned short* bp0 = wdt_e + (size_t)(n0 + srow) * DFF + scol;
  const unsigned short* bp1 = bp0 + (size_t)64 * DFF;
  unsigned short* as0 = As + tid * 8;
  unsigned short* as1 = As + (256 + tid) * 8;
  unsigned short* bs0 = Bs + tid * 8;
  unsigned short* bs1 = Bs + (256 + tid) * 8;
  const int fr = lane & 15, kq = (lane >> 4) * 8;
  for (int k0 = 0; k0 < DFF; k0 += 32) {
    __syncthreads();
    gld16(ap0 + k0, as0); gld16(ap1 + k0, as1);
    gld16(bp0 + k0, bs0); gld16(bp1 + k0, bs1);
    __syncthreads();
    bf16x8 af[4], bf[4];
#pragma unroll
    for (int mi = 0; mi < 4; mi++) af[mi] = *(const bf16x8*)(As + (wm + mi * 16 + fr) * 32 + kq);
#pragma unroll
    for (int ni = 0; ni < 4; ni++) bf[ni] = *(const bf16x8*)(Bs + (wn + ni * 16 + fr) * 32 + kq);
#pragma unroll
    for (int mi = 0; mi < 4; mi++)
#pragma unroll
      for (int ni = 0; ni < 4; ni++)
        acc[mi][ni] = __builtin_amdgcn_mfma_f32_16x16x32_bf16(af[mi], bf[ni], acc[mi][ni], 0, 0, 0);
  }
  const int rb0 = wm + (lane >> 4) * 4;
  const int cb0 = n0 + wn + fr;
#pragma unroll
  for (int mi = 0; mi < 4; mi++)
#pragma unroll
    for (int r = 0; r < 4; r++) {
      int lrow = rb0 + mi * 16 + r;
      if (ent.y < 0) {
        int tok = ent.z + lrow;
#pragma unroll
        for (int ni = 0; ni < 4; ni++)
          out[(size_t)tok * DIM + cb0 + ni * 16] = acc[mi][ni][r];
      } else {
        int tok = idxR[ent.y + lrow];
        float s = wslR[ent.y + lrow];
        if (s != 0.f) {
#pragma unroll
          for (int ni = 0; ni < 4; ni++)
            atomicAdd(&out[(size_t)tok * DIM + cb0 + ni * 16], s * acc[mi][ni][r]);
        }
      }
    }
}

// ---------------- combine: out[t] = y[t] + w1*y[p1] + w2*y[p2] ----------------
__global__ __launch_bounds__(256) void combine_kernel(const float* __restrict__ y,
                                                      const int4* __restrict__ tokE,
                                                      const float2* __restrict__ tokW,
                                                      const int* __restrict__ pref,
                                                      float* __restrict__ out) {
  const int t = blockIdx.x;
  const int c = threadIdx.x * 4;
  int4 te = tokE[t];
  float2 tw = tokW[t];
  int p1 = 4096 + pref[te.x] * 128 + te.y;
  int p2 = 4096 + pref[te.z] * 128 + te.w;
  float4 a = *(const float4*)(y + (size_t)t * DIM + c);
  float4 b = *(const float4*)(y + (size_t)p1 * DIM + c);
  float4 d = *(const float4*)(y + (size_t)p2 * DIM + c);
  float4 o;
  o.x = a.x + tw.x * b.x + tw.y * d.x;
  o.y = a.y + tw.x * b.y + tw.y * d.y;
  o.z = a.z + tw.x * b.z + tw.y * d.z;
  o.w = a.w + tw.x * b.w + tw.y * d.w;
  *(float4*)(out + (size_t)t * DIM + c) = o;
}

extern "C" void kernel_launch(void* const* d_in, const int* in_sizes, int n_in,
                              void* d_out, int out_size, void* d_ws, size_t ws_size,
                              hipStream_t stream) {
  const float* x  = (const float*)d_in[0];
  const float* rw = (const float*)d_in[1];
  const float* rb = (const float*)d_in[2];
  const float* wg = (const float*)d_in[3];
  const float* wu = (const float*)d_in[4];
  const float* wd = (const float*)d_in[5];
  float* out = (float*)d_out;

  // mode A2: unified, atomic-free (y aliases dead wgt/wut); needs ~163.28 MB (ws known >= 163.32 MB)
  // mode B : sequential e0 + routed, atomic gemm2; needs ~146.7 MB
  // mode C : per-expert loop, atomic gemm2
  const bool modeA = ws_size >= (size_t)163300000;
  const bool modeB = !modeA && ws_size >= (size_t)146700000;
  const size_t H_ROWS = modeA ? 13184 : (modeB ? 9088 : 4096);
  const int rsb = modeA ? 4096 : 0;

  char* p = (char*)d_ws;
  unsigned short* xb  = (unsigned short*)p; p += (size_t)T_TOK * DIM * 2;       // 8,388,608
  unsigned short* h   = (unsigned short*)p; p += H_ROWS * DFF * 2;
  unsigned short* wgt = (unsigned short*)p;                                     // y aliases wgt+wut in mode A
  float*          y   = (float*)p;          p += (size_t)NE * DIM * DFF * 2;
  unsigned short* wut = (unsigned short*)p; p += (size_t)NE * DIM * DFF * 2;
  unsigned short* wdt = (unsigned short*)p; p += (size_t)NE * DIM * DFF * 2;
  int*   idxR = (int*)p;   p += (size_t)NR * 4096 * 4;                          // 114,688
  float* wslR;
  if (modeA) { wslR = (float*)wdt; }                                            // scratch: overwritten by transpose later
  else       { wslR = (float*)p; p += (size_t)NR * 4096 * 4; }
  int*   cnt  = (int*)p;      p += 64;
  int*   pref = (int*)p;      p += 64;
  int4*  schedAll = (int4*)p; p += 2048;
  int4*  schedP   = (int4*)p; p += 4096;
  int4*  tokE = (int4*)p;     p += (size_t)T_TOK * 16;
  float2* tokW = (float2*)p;  p += (size_t)T_TOK * 8;

  cvt_x_kernel<<<dim3(T_TOK * DIM / 4 / 256), 256, 0, stream>>>((const float4*)x, (ushort4*)xb);
  hipMemsetAsync(cnt, 0, 64, stream);
  router_kernel<<<dim3(T_TOK / 4), 256, 0, stream>>>(x, rw, rb, idxR, wslR, cnt, tokE, tokW);
  sched_kernel<<<dim3(1), 256, 0, stream>>>(cnt, idxR, wslR, schedAll, schedP, pref, rsb);
  transpose_cvt_kernel<<<dim3(64, 32, 24), 256, 0, stream>>>(wg, wu, wd, wgt, wut, wdt);

  if (modeA) {
    gemm1_kernel<<<dim3((DFF / 128) * NY), 512, 0, stream>>>(xb, wgt, wut, idxR, schedAll, h, NY);
    gemm2_kernel<<<dim3((DIM / 256) * NY), 512, 0, stream>>>(h, wdt, schedAll, y, DIM / 256);
    combine_kernel<<<dim3(T_TOK), 256, 0, stream>>>(y, tokE, tokW, pref, out);
  } else if (modeB) {
    gemm1_kernel<<<dim3((DFF / 128) * 32), 512, 0, stream>>>(xb, wgt, wut, idxR, schedAll, h, 32);
    gemm2_atomic_kernel<<<dim3(DIM / 128, 32), 256, 0, stream>>>(h, wdt, idxR, wslR, schedAll, out);
    gemm1_kernel<<<dim3((DFF / 128) * MAXNB), 512, 0, stream>>>(xb, wgt, wut, idxR, schedAll + 32, h, MAXNB);
    gemm2_atomic_kernel<<<dim3(DIM / 128, MAXNB), 256, 0, stream>>>(h, wdt, idxR, wslR, schedAll + 32, out);
  } else {
    gemm1_kernel<<<dim3((DFF / 128) * 32), 512, 0, stream>>>(xb, wgt, wut, idxR, schedAll, h, 32);
    gemm2_atomic_kernel<<<dim3(DIM / 128, 32), 256, 0, stream>>>(h, wdt, idxR, wslR, schedAll, out);
    for (int e = 0; e < NR; e++) {
      gemm1_kernel<<<dim3((DFF / 128) * 32), 512, 0, stream>>>(xb, wgt, wut, idxR, schedP + e * 32, h, 32);
      gemm2_atomic_kernel<<<dim3(DIM / 128, 32), 256, 0, stream>>>(h, wdt, idxR, wslR, schedP + e * 32, out);
    }
  }
}